// Round 1
// baseline (427.004 us; speedup 1.0000x reference)
//
#include <hip/hip_runtime.h>

#define NTOK 49
#define NH 6
#define HD 32
#define DIM 192
#define QKV_DIM 576
#define PI_F 3.14159265358979323846f

typedef __bf16 bf16_t;
typedef __bf16 bf16x8 __attribute__((ext_vector_type(8)));
typedef float f32x4 __attribute__((ext_vector_type(4)));

// ---------------- Kernel 0: convert weights fp32 -> bf16 ----------------
__global__ __launch_bounds__(256) void cvt_weights(const float* __restrict__ qkv_w,
                                                   const float* __restrict__ proj_w,
                                                   bf16_t* __restrict__ wq,
                                                   bf16_t* __restrict__ wp) {
    int idx = blockIdx.x * 256 + threadIdx.x;
    if (idx < QKV_DIM * DIM) {
        wq[idx] = (bf16_t)qkv_w[idx];
    } else {
        int j = idx - QKV_DIM * DIM;
        if (j < DIM * DIM) wp[j] = (bf16_t)proj_w[j];
    }
}

// ---------------- Kernel 1: QKV projection GEMM (bf16 MFMA) ----------------
// C[M x 576] = X[M x 192] @ qkv_w^T + qkv_b ; scatter into q(scaled)/k/v bf16
__global__ __launch_bounds__(256) void qkv_gemm(const float* __restrict__ x,
                                                const bf16_t* __restrict__ wq,
                                                const float* __restrict__ qkv_b,
                                                bf16_t* __restrict__ qb,
                                                bf16_t* __restrict__ kb,
                                                bf16_t* __restrict__ vb) {
    __shared__ bf16_t a_sh[64 * 200];
    __shared__ bf16_t w_sh[64 * 200];
    const int tid  = threadIdx.x;
    const int wave = tid >> 6;
    const int lane = tid & 63;
    const int quad = lane >> 4;
    const int l16  = lane & 15;
    const int bm0  = blockIdx.x * 64;

    // stage A tile (64 x 192) fp32 -> bf16 LDS, once
#pragma unroll
    for (int it = 0; it < 12; ++it) {
        int e = (tid + it * 256) * 4;
        int r = e / 192, c = e % 192;
        const float4 xv = *(const float4*)(x + (bm0 + r) * DIM + c);
        bf16_t* dst = &a_sh[r * 200 + c];
        dst[0] = (bf16_t)xv.x; dst[1] = (bf16_t)xv.y;
        dst[2] = (bf16_t)xv.z; dst[3] = (bf16_t)xv.w;
    }

    const float scale = 0.17677669529663687f; // 32^-0.5

    for (int nc = 0; nc < 9; ++nc) {
        __syncthreads();
        // stage W tile: rows [nc*64, nc*64+64) x 192, bf16
#pragma unroll
        for (int it = 0; it < 6; ++it) {
            int e = (tid + it * 256) * 8;
            int r = e / 192, c = e % 192;
            uint4 wv = *(const uint4*)(wq + (nc * 64 + r) * DIM + c);
            *(uint4*)(&w_sh[r * 200 + c]) = wv;
        }
        __syncthreads();

        f32x4 acc[4] = {};
#pragma unroll
        for (int ks = 0; ks < 6; ++ks) {
            bf16x8 af = *(const bf16x8*)(&a_sh[(wave * 16 + l16) * 200 + ks * 32 + quad * 8]);
#pragma unroll
            for (int ct = 0; ct < 4; ++ct) {
                bf16x8 bfv = *(const bf16x8*)(&w_sh[(ct * 16 + l16) * 200 + ks * 32 + quad * 8]);
                acc[ct] = __builtin_amdgcn_mfma_f32_16x16x32_bf16(af, bfv, acc[ct], 0, 0, 0);
            }
        }
        // epilogue: scatter into q/k/v with layout ((b*6+h)*49 + t)*32 + d
#pragma unroll
        for (int ct = 0; ct < 4; ++ct) {
            int cg = nc * 64 + ct * 16 + l16;       // output channel in [0,576)
            int which = cg / 192;
            int rem = cg % 192;
            int h = rem >> 5, d = rem & 31;
            float bias = qkv_b[cg];
            bf16_t* outp = (which == 0) ? qb : (which == 1) ? kb : vb;
            float sc = (which == 0) ? scale : 1.0f;
#pragma unroll
            for (int r = 0; r < 4; ++r) {
                int m = bm0 + wave * 16 + quad * 4 + r;
                int b = m / 49, t = m % 49;
                float val = (acc[ct][r] + bias) * sc;
                outp[((b * NH + h) * 49 + t) * 32 + d] = (bf16_t)val;
            }
        }
    }
}

// ---------------- Kernel 2: fused window attention, one wave per (b,h) ----------------
__global__ __launch_bounds__(64) void attn_kernel(const bf16_t* __restrict__ q,
                                                  const bf16_t* __restrict__ k,
                                                  const bf16_t* __restrict__ v,
                                                  const float* __restrict__ Dp,
                                                  const float* __restrict__ a_p,
                                                  const float* __restrict__ b_p,
                                                  const float* __restrict__ a_r,
                                                  const float* __restrict__ b_r,
                                                  bf16_t* __restrict__ attn_out) {
    __shared__ float qs[49 * 33];
    __shared__ float ks[49 * 32];
    __shared__ float vs[49 * 32];
    __shared__ float Ss[49 * 53];
    __shared__ float bias13[169];

    const int bh = blockIdx.x;
    const int b = bh / NH, h = bh % NH;
    const int tid = threadIdx.x;

    const bf16_t* qg = q + bh * (49 * 32);
    const bf16_t* kg = k + bh * (49 * 32);
    const bf16_t* vg = v + bh * (49 * 32);

    // stage q,k,v (49x32 bf16) -> fp32 LDS
    for (int u = tid; u < 196; u += 64) {
        int e = u * 8;
        int r = e >> 5, c = e & 31;
        bf16x8 qv = *(const bf16x8*)(qg + e);
        bf16x8 kv = *(const bf16x8*)(kg + e);
        bf16x8 vv = *(const bf16x8*)(vg + e);
#pragma unroll
        for (int t = 0; t < 8; ++t) {
            qs[r * 33 + c + t] = (float)qv[t];
            ks[r * 32 + c + t] = (float)kv[t];
            vs[r * 32 + c + t] = (float)vv[t];
        }
    }

    // bias table over (dr, da) in [-6,6]^2
    float Dv = Dp[b];
    for (int u = tid; u < 169; u += 64) {
        int dr = u / 13 - 6, da = u % 13 - 6;
        int ri = (dr < 0) ? dr + 13 : dr;
        int ai = (da < 0) ? da + 13 : da;
        float ang_a = (float)da * (2.0f * PI_F / 56.0f);
        float ang_r = Dv * (float)dr * (2.0f * PI_F / 448.0f);
        bias13[u] = a_p[ai * NH + h] * __cosf(ang_a) + b_p[ai * NH + h] * __sinf(ang_a)
                  + a_r[ri * NH + h] * __cosf(ang_r) + b_r[ri * NH + h] * __sinf(ang_r);
    }
    __syncthreads();

    if (tid < 49) {
        const int i = tid;
        const int ihi = i / 7, iwi = i % 7;
        float qr[32];
#pragma unroll
        for (int kk = 0; kk < 32; ++kk) qr[kk] = qs[i * 33 + kk];

        // scores + bias
        int jh = 0, jw = 0;
        for (int j = 0; j < 49; ++j) {
            float s0 = 0.f, s1 = 0.f, s2 = 0.f, s3 = 0.f;
#pragma unroll
            for (int kk = 0; kk < 32; kk += 4) {
                s0 += qr[kk]     * ks[j * 32 + kk];
                s1 += qr[kk + 1] * ks[j * 32 + kk + 1];
                s2 += qr[kk + 2] * ks[j * 32 + kk + 2];
                s3 += qr[kk + 3] * ks[j * 32 + kk + 3];
            }
            int dr = ihi - jh, da = iwi - jw;
            Ss[i * 53 + j] = (s0 + s1) + (s2 + s3) + bias13[(dr + 6) * 13 + (da + 6)];
            if (++jw == 7) { jw = 0; ++jh; }
        }

        // softmax along j (row owned by this lane; no cross-lane needed)
        float mx = -1e30f;
        for (int j = 0; j < 49; ++j) mx = fmaxf(mx, Ss[i * 53 + j]);
        float sum = 0.f;
        for (int j = 0; j < 49; ++j) {
            float e = __expf(Ss[i * 53 + j] - mx);
            Ss[i * 53 + j] = e;
            sum += e;
        }
        float rs = 1.0f / sum;

        // O = P @ V (unnormalized, scale at end)
        float O[32];
#pragma unroll
        for (int d2 = 0; d2 < 32; ++d2) O[d2] = 0.f;
        for (int j = 0; j < 49; ++j) {
            float p = Ss[i * 53 + j];
#pragma unroll
            for (int d2 = 0; d2 < 32; ++d2) O[d2] += p * vs[j * 32 + d2];
        }

        bf16_t* op = attn_out + (b * 49 + i) * DIM + h * 32;
#pragma unroll
        for (int d2 = 0; d2 < 32; d2 += 8) {
            bf16x8 pk;
#pragma unroll
            for (int t = 0; t < 8; ++t) pk[t] = (bf16_t)(O[d2 + t] * rs);
            *(bf16x8*)(op + d2) = pk;
        }
    }
}

// ---------------- Kernel 3: output projection GEMM (bf16 MFMA, fp32 out) ----------------
__global__ __launch_bounds__(256) void proj_gemm(const bf16_t* __restrict__ a,
                                                 const bf16_t* __restrict__ wp,
                                                 const float* __restrict__ proj_b,
                                                 float* __restrict__ out) {
    __shared__ bf16_t a_sh[64 * 200];
    __shared__ bf16_t w_sh[64 * 200];
    const int tid  = threadIdx.x;
    const int wave = tid >> 6;
    const int lane = tid & 63;
    const int quad = lane >> 4;
    const int l16  = lane & 15;
    const int bm0  = blockIdx.x * 64;

    // stage A tile (64 x 192) bf16
#pragma unroll
    for (int it = 0; it < 6; ++it) {
        int e = (tid + it * 256) * 8;
        int r = e / 192, c = e % 192;
        uint4 av = *(const uint4*)(a + (bm0 + r) * DIM + c);
        *(uint4*)(&a_sh[r * 200 + c]) = av;
    }

    for (int nc = 0; nc < 3; ++nc) {
        __syncthreads();
#pragma unroll
        for (int it = 0; it < 6; ++it) {
            int e = (tid + it * 256) * 8;
            int r = e / 192, c = e % 192;
            uint4 wv = *(const uint4*)(wp + (nc * 64 + r) * DIM + c);
            *(uint4*)(&w_sh[r * 200 + c]) = wv;
        }
        __syncthreads();

        f32x4 acc[4] = {};
#pragma unroll
        for (int ks = 0; ks < 6; ++ks) {
            bf16x8 af = *(const bf16x8*)(&a_sh[(wave * 16 + l16) * 200 + ks * 32 + quad * 8]);
#pragma unroll
            for (int ct = 0; ct < 4; ++ct) {
                bf16x8 bfv = *(const bf16x8*)(&w_sh[(ct * 16 + l16) * 200 + ks * 32 + quad * 8]);
                acc[ct] = __builtin_amdgcn_mfma_f32_16x16x32_bf16(af, bfv, acc[ct], 0, 0, 0);
            }
        }
#pragma unroll
        for (int ct = 0; ct < 4; ++ct) {
            int cg = nc * 64 + ct * 16 + l16;
            float bias = proj_b[cg];
#pragma unroll
            for (int r = 0; r < 4; ++r) {
                int m = bm0 + wave * 16 + quad * 4 + r;
                out[m * DIM + cg] = acc[ct][r] + bias;
            }
        }
    }
}

extern "C" void kernel_launch(void* const* d_in, const int* in_sizes, int n_in,
                              void* d_out, int out_size, void* d_ws, size_t ws_size,
                              hipStream_t stream) {
    const float* x      = (const float*)d_in[0];
    const float* D      = (const float*)d_in[1];
    const float* qkv_w  = (const float*)d_in[2];
    const float* qkv_b  = (const float*)d_in[3];
    const float* proj_w = (const float*)d_in[4];
    const float* proj_b = (const float*)d_in[5];
    const float* a_p    = (const float*)d_in[6];
    const float* b_p    = (const float*)d_in[7];
    const float* a_r    = (const float*)d_in[8];
    const float* b_r    = (const float*)d_in[9];
    float* out = (float*)d_out;

    const int B_ = in_sizes[0] / (NTOK * DIM);   // 2048
    const int M  = B_ * NTOK;                    // 100352

    char* w = (char*)d_ws;
    bf16_t* wq = (bf16_t*)w; w += (size_t)QKV_DIM * DIM * 2;
    bf16_t* wp = (bf16_t*)w; w += (size_t)DIM * DIM * 2;
    size_t headbuf = (size_t)B_ * NH * 49 * 32 * 2;
    bf16_t* qb = (bf16_t*)w; w += headbuf;
    bf16_t* kb = (bf16_t*)w; w += headbuf;
    bf16_t* vb = (bf16_t*)w; w += headbuf;
    bf16_t* ao = (bf16_t*)w; w += (size_t)M * DIM * 2;

    cvt_weights<<<dim3((QKV_DIM * DIM + DIM * DIM + 255) / 256), dim3(256), 0, stream>>>(
        qkv_w, proj_w, wq, wp);

    qkv_gemm<<<dim3(M / 64), dim3(256), 0, stream>>>(x, wq, qkv_b, qb, kb, vb);

    attn_kernel<<<dim3(B_ * NH), dim3(64), 0, stream>>>(qb, kb, vb, D, a_p, b_p, a_r, b_r, ao);

    proj_gemm<<<dim3(M / 64), dim3(256), 0, stream>>>(ao, wp, proj_b, out);
}

// Round 2
// 298.394 us; speedup vs baseline: 1.4310x; 1.4310x over previous
//
#include <hip/hip_runtime.h>

#define NTOK 49
#define NH 6
#define HD 32
#define DIM 192
#define QKV_DIM 576
#define PI_F 3.14159265358979323846f

typedef __bf16 bf16_t;
typedef __bf16 bf16x8 __attribute__((ext_vector_type(8)));
typedef float f32x4 __attribute__((ext_vector_type(4)));

// ---------------- Kernel 0: convert weights fp32 -> bf16 ----------------
__global__ __launch_bounds__(256) void cvt_weights(const float* __restrict__ qkv_w,
                                                   const float* __restrict__ proj_w,
                                                   bf16_t* __restrict__ wq,
                                                   bf16_t* __restrict__ wp) {
    int idx = blockIdx.x * 256 + threadIdx.x;
    if (idx < QKV_DIM * DIM) {
        wq[idx] = (bf16_t)qkv_w[idx];
    } else {
        int j = idx - QKV_DIM * DIM;
        if (j < DIM * DIM) wp[j] = (bf16_t)proj_w[j];
    }
}

// ---------------- Kernel 1: QKV projection GEMM (bf16 MFMA) ----------------
// C[M x 576] = X[M x 192] @ qkv_w^T + qkv_b ; scatter into q(scaled)/k row-major,
// v TRANSPOSED per head: vb[bh][d][t] with row stride 64 (cols 49..63 unwritten).
__global__ __launch_bounds__(256) void qkv_gemm(const float* __restrict__ x,
                                                const bf16_t* __restrict__ wq,
                                                const float* __restrict__ qkv_b,
                                                bf16_t* __restrict__ qb,
                                                bf16_t* __restrict__ kb,
                                                bf16_t* __restrict__ vb) {
    __shared__ bf16_t a_sh[64 * 200];
    __shared__ bf16_t w_sh[64 * 200];
    const int tid  = threadIdx.x;
    const int wave = tid >> 6;
    const int lane = tid & 63;
    const int quad = lane >> 4;
    const int l16  = lane & 15;
    const int bm0  = blockIdx.x * 64;

    // stage A tile (64 x 192) fp32 -> bf16 LDS, once
#pragma unroll
    for (int it = 0; it < 12; ++it) {
        int e = (tid + it * 256) * 4;
        int r = e / 192, c = e % 192;
        const float4 xv = *(const float4*)(x + (bm0 + r) * DIM + c);
        bf16_t* dst = &a_sh[r * 200 + c];
        dst[0] = (bf16_t)xv.x; dst[1] = (bf16_t)xv.y;
        dst[2] = (bf16_t)xv.z; dst[3] = (bf16_t)xv.w;
    }

    const float scale = 0.17677669529663687f; // 32^-0.5

    for (int nc = 0; nc < 9; ++nc) {
        __syncthreads();
        // stage W tile: rows [nc*64, nc*64+64) x 192, bf16
#pragma unroll
        for (int it = 0; it < 6; ++it) {
            int e = (tid + it * 256) * 8;
            int r = e / 192, c = e % 192;
            uint4 wv = *(const uint4*)(wq + (nc * 64 + r) * DIM + c);
            *(uint4*)(&w_sh[r * 200 + c]) = wv;
        }
        __syncthreads();

        f32x4 acc[4] = {};
#pragma unroll
        for (int ks = 0; ks < 6; ++ks) {
            bf16x8 af = *(const bf16x8*)(&a_sh[(wave * 16 + l16) * 200 + ks * 32 + quad * 8]);
#pragma unroll
            for (int ct = 0; ct < 4; ++ct) {
                bf16x8 bfv = *(const bf16x8*)(&w_sh[(ct * 16 + l16) * 200 + ks * 32 + quad * 8]);
                acc[ct] = __builtin_amdgcn_mfma_f32_16x16x32_bf16(af, bfv, acc[ct], 0, 0, 0);
            }
        }
        // epilogue
#pragma unroll
        for (int ct = 0; ct < 4; ++ct) {
            int cg = nc * 64 + ct * 16 + l16;       // output channel in [0,576)
            int which = cg / 192;
            int rem = cg % 192;
            int h = rem >> 5, d = rem & 31;
            float bias = qkv_b[cg];
            float sc = (which == 0) ? scale : 1.0f;
#pragma unroll
            for (int r = 0; r < 4; ++r) {
                int m = bm0 + wave * 16 + quad * 4 + r;
                int b = m / 49, t = m % 49;
                float val = (acc[ct][r] + bias) * sc;
                int bh = b * NH + h;
                if (which == 0)      qb[(bh * 49 + t) * 32 + d] = (bf16_t)val;
                else if (which == 1) kb[(bh * 49 + t) * 32 + d] = (bf16_t)val;
                else                 vb[((size_t)bh * 32 + d) * 64 + t] = (bf16_t)val;
            }
        }
    }
}

// ---------------- Kernel 2: MFMA window attention, one wave per (b,h) ----------------
// S = Q K^T via 4x4 tiles of mfma_16x16x32 (padded 49->64); softmax in C-frag
// layout with shfl_xor butterflies; P -> LDS -> A-frag; O = P V with V read
// transposed from global. Only P (2.3 KB) + bias table in LDS.
__global__ __launch_bounds__(64) void attn_mfma(const bf16_t* __restrict__ q,
                                                const bf16_t* __restrict__ k,
                                                const bf16_t* __restrict__ v,
                                                const float* __restrict__ Dp,
                                                const float* __restrict__ a_p,
                                                const float* __restrict__ b_p,
                                                const float* __restrict__ a_r,
                                                const float* __restrict__ b_r,
                                                bf16_t* __restrict__ attn_out) {
    __shared__ float bias13[169];
    __shared__ bf16_t P[16 * 72];   // stride 72: 16B-aligned rows, <=2-way banks

    const int bh = blockIdx.x;
    const int b = bh / NH, h = bh % NH;
    const int lane = threadIdx.x;
    const int l16 = lane & 15;
    const int quad = lane >> 4;

    // bias table over (dr, da) in [-6,6]^2
    const float Dv = Dp[b];
    for (int u = lane; u < 169; u += 64) {
        int dr = u / 13 - 6, da = u % 13 - 6;
        int ri = (dr < 0) ? dr + 13 : dr;
        int ai = (da < 0) ? da + 13 : da;
        float ang_a = (float)da * (2.0f * PI_F / 56.0f);
        float ang_r = Dv * (float)dr * (2.0f * PI_F / 448.0f);
        bias13[u] = a_p[ai * NH + h] * __cosf(ang_a) + b_p[ai * NH + h] * __sinf(ang_a)
                  + a_r[ri * NH + h] * __cosf(ang_r) + b_r[ri * NH + h] * __sinf(ang_r);
    }
    __syncthreads();

    const bf16_t* qg = q + (size_t)bh * 1568;
    const bf16_t* kg = k + (size_t)bh * 1568;
    const bf16_t* vg = v + (size_t)bh * 2048;

    // K B-frags: B[k=d][n=j] = K[j][d], lane n=l16 -> j, k=quad*8+t -> d
    bf16x8 kf[4];
#pragma unroll
    for (int nt = 0; nt < 4; ++nt)
        kf[nt] = *(const bf16x8*)(kg + (nt * 16 + l16) * 32 + quad * 8);
    // V B-frags: B[k=j][n=d] = VT[d][j], lane n=l16 -> d, k=quad*8+t -> j
    bf16x8 vf[2][2];
#pragma unroll
    for (int ntd = 0; ntd < 2; ++ntd)
#pragma unroll
        for (int kt = 0; kt < 2; ++kt)
            vf[ntd][kt] = *(const bf16x8*)(vg + (ntd * 16 + l16) * 64 + kt * 32 + quad * 8);

    int jh[4], jw[4];
#pragma unroll
    for (int nt = 0; nt < 4; ++nt) {
        int j = nt * 16 + l16;
        jh[nt] = j / 7;
        jw[nt] = j - 7 * jh[nt];
    }

    for (int mt = 0; mt < 4; ++mt) {
        // Q A-frag: A[m=i][k=d], lane m=l16 -> i, k=quad*8+t -> d
        bf16x8 qf = *(const bf16x8*)(qg + (mt * 16 + l16) * 32 + quad * 8);

        f32x4 s[4] = {};
#pragma unroll
        for (int nt = 0; nt < 4; ++nt)
            s[nt] = __builtin_amdgcn_mfma_f32_16x16x32_bf16(qf, kf[nt], s[nt], 0, 0, 0);

        // bias + mask + softmax per row (row = mt*16 + quad*4 + r, col = nt*16+l16)
        float ev[4][4];
        float rs[4];
#pragma unroll
        for (int r = 0; r < 4; ++r) {
            int i = mt * 16 + quad * 4 + r;
            int ih = i / 7, iw = i - 7 * ih;
            float val[4];
            float mx = -1e30f;
#pragma unroll
            for (int nt = 0; nt < 4; ++nt) {
                int j = nt * 16 + l16;
                int idx = (ih - jh[nt] + 6) * 13 + (iw - jw[nt] + 6);
                idx = min(max(idx, 0), 168);   // garbage rows i>=49 stay in-table
                float vv = s[nt][r] + bias13[idx];
                if (j >= 49) vv = -1e30f;
                val[nt] = vv;
                mx = fmaxf(mx, vv);
            }
#pragma unroll
            for (int m = 1; m <= 8; m <<= 1) mx = fmaxf(mx, __shfl_xor(mx, m));
            float sum = 0.f;
#pragma unroll
            for (int nt = 0; nt < 4; ++nt) {
                float e = __expf(val[nt] - mx);
                ev[r][nt] = e;
                sum += e;
            }
#pragma unroll
            for (int m = 1; m <= 8; m <<= 1) sum += __shfl_xor(sum, m);
            rs[r] = 1.0f / sum;
        }

        // P -> LDS (C-frag scatter), then read back as A-frags
#pragma unroll
        for (int r = 0; r < 4; ++r)
#pragma unroll
            for (int nt = 0; nt < 4; ++nt)
                P[(quad * 4 + r) * 72 + nt * 16 + l16] = (bf16_t)ev[r][nt];
        __syncthreads();

        bf16x8 pa[2];
#pragma unroll
        for (int kt = 0; kt < 2; ++kt)
            pa[kt] = *(const bf16x8*)(&P[l16 * 72 + kt * 32 + quad * 8]);

        f32x4 o[2] = {};
#pragma unroll
        for (int ntd = 0; ntd < 2; ++ntd)
#pragma unroll
            for (int kt = 0; kt < 2; ++kt)
                o[ntd] = __builtin_amdgcn_mfma_f32_16x16x32_bf16(pa[kt], vf[ntd][kt], o[ntd], 0, 0, 0);

        // store O rows (normalize by row sum)
#pragma unroll
        for (int r = 0; r < 4; ++r) {
            int i = mt * 16 + quad * 4 + r;
            if (i < 49) {
                bf16_t* op = attn_out + ((size_t)(b * 49 + i)) * DIM + h * 32;
                op[l16]      = (bf16_t)(o[0][r] * rs[r]);
                op[16 + l16] = (bf16_t)(o[1][r] * rs[r]);
            }
        }
        __syncthreads();   // protect P before next mt overwrites it
    }
}

// ---------------- Kernel 3: output projection GEMM (bf16 MFMA, fp32 out) ----------------
__global__ __launch_bounds__(256) void proj_gemm(const bf16_t* __restrict__ a,
                                                 const bf16_t* __restrict__ wp,
                                                 const float* __restrict__ proj_b,
                                                 float* __restrict__ out) {
    __shared__ bf16_t a_sh[64 * 200];
    __shared__ bf16_t w_sh[64 * 200];
    const int tid  = threadIdx.x;
    const int wave = tid >> 6;
    const int lane = tid & 63;
    const int quad = lane >> 4;
    const int l16  = lane & 15;
    const int bm0  = blockIdx.x * 64;

    // stage A tile (64 x 192) bf16
#pragma unroll
    for (int it = 0; it < 6; ++it) {
        int e = (tid + it * 256) * 8;
        int r = e / 192, c = e % 192;
        uint4 av = *(const uint4*)(a + (bm0 + r) * DIM + c);
        *(uint4*)(&a_sh[r * 200 + c]) = av;
    }

    for (int nc = 0; nc < 3; ++nc) {
        __syncthreads();
#pragma unroll
        for (int it = 0; it < 6; ++it) {
            int e = (tid + it * 256) * 8;
            int r = e / 192, c = e % 192;
            uint4 wv = *(const uint4*)(wp + (nc * 64 + r) * DIM + c);
            *(uint4*)(&w_sh[r * 200 + c]) = wv;
        }
        __syncthreads();

        f32x4 acc[4] = {};
#pragma unroll
        for (int ks = 0; ks < 6; ++ks) {
            bf16x8 af = *(const bf16x8*)(&a_sh[(wave * 16 + l16) * 200 + ks * 32 + quad * 8]);
#pragma unroll
            for (int ct = 0; ct < 4; ++ct) {
                bf16x8 bfv = *(const bf16x8*)(&w_sh[(ct * 16 + l16) * 200 + ks * 32 + quad * 8]);
                acc[ct] = __builtin_amdgcn_mfma_f32_16x16x32_bf16(af, bfv, acc[ct], 0, 0, 0);
            }
        }
#pragma unroll
        for (int ct = 0; ct < 4; ++ct) {
            int cg = nc * 64 + ct * 16 + l16;
            float bias = proj_b[cg];
#pragma unroll
            for (int r = 0; r < 4; ++r) {
                int m = bm0 + wave * 16 + quad * 4 + r;
                out[m * DIM + cg] = acc[ct][r] + bias;
            }
        }
    }
}

extern "C" void kernel_launch(void* const* d_in, const int* in_sizes, int n_in,
                              void* d_out, int out_size, void* d_ws, size_t ws_size,
                              hipStream_t stream) {
    const float* x      = (const float*)d_in[0];
    const float* D      = (const float*)d_in[1];
    const float* qkv_w  = (const float*)d_in[2];
    const float* qkv_b  = (const float*)d_in[3];
    const float* proj_w = (const float*)d_in[4];
    const float* proj_b = (const float*)d_in[5];
    const float* a_p    = (const float*)d_in[6];
    const float* b_p    = (const float*)d_in[7];
    const float* a_r    = (const float*)d_in[8];
    const float* b_r    = (const float*)d_in[9];
    float* out = (float*)d_out;

    const int B_ = in_sizes[0] / (NTOK * DIM);   // 2048
    const int M  = B_ * NTOK;                    // 100352
    const int BH = B_ * NH;                      // 12288

    char* w = (char*)d_ws;
    bf16_t* wq = (bf16_t*)w; w += (size_t)QKV_DIM * DIM * 2;
    bf16_t* wp = (bf16_t*)w; w += (size_t)DIM * DIM * 2;
    size_t headbuf = (size_t)BH * 49 * 32 * 2 + 4096;   // +slack for padded frag reads
    bf16_t* qb = (bf16_t*)w; w += headbuf;
    bf16_t* kb = (bf16_t*)w; w += headbuf;
    bf16_t* vb = (bf16_t*)w; w += (size_t)BH * 32 * 64 * 2;   // transposed+padded V
    bf16_t* ao = (bf16_t*)w; w += (size_t)M * DIM * 2;

    cvt_weights<<<dim3((QKV_DIM * DIM + DIM * DIM + 255) / 256), dim3(256), 0, stream>>>(
        qkv_w, proj_w, wq, wp);

    qkv_gemm<<<dim3(M / 64), dim3(256), 0, stream>>>(x, wq, qkv_b, qb, kb, vb);

    attn_mfma<<<dim3(BH), dim3(64), 0, stream>>>(qb, kb, vb, D, a_p, b_p, a_r, b_r, ao);

    proj_gemm<<<dim3(M / 64), dim3(256), 0, stream>>>(ao, wp, proj_b, out);
}

// Round 3
// 292.003 us; speedup vs baseline: 1.4623x; 1.0219x over previous
//
#include <hip/hip_runtime.h>

#define NTOK 49
#define NH 6
#define HD 32
#define DIM 192
#define QKV_DIM 576
#define PI_F 3.14159265358979323846f

typedef __bf16 bf16_t;
typedef __bf16 bf16x4 __attribute__((ext_vector_type(4)));
typedef __bf16 bf16x8 __attribute__((ext_vector_type(8)));
typedef float f32x4 __attribute__((ext_vector_type(4)));

// ---------------- Kernel 0: convert weights fp32 -> bf16 ----------------
__global__ __launch_bounds__(256) void cvt_weights(const float* __restrict__ qkv_w,
                                                   const float* __restrict__ proj_w,
                                                   bf16_t* __restrict__ wq,
                                                   bf16_t* __restrict__ wp) {
    int idx = blockIdx.x * 256 + threadIdx.x;
    if (idx < QKV_DIM * DIM) {
        wq[idx] = (bf16_t)qkv_w[idx];
    } else {
        int j = idx - QKV_DIM * DIM;
        if (j < DIM * DIM) wp[j] = (bf16_t)proj_w[j];
    }
}

// ---------------- Kernel 1: fully-fused window attention ----------------
// One block (384 thr = 6 waves) per window; wave w = head w.
// Phases: stage x -> [sync] -> x A-frags to regs -> [sync] ->
//   per-wave: QKV gemm (weights from L2-hot global) -> q/k/vt to private LDS ->
//   MFMA attention (R2-verified) -> O into x buffer (reused) -> [sync] ->
//   proj gemm -> fp32 out.
__global__ __launch_bounds__(384) void fused_win_attn(
        const float* __restrict__ x,
        const float* __restrict__ Dp,
        const bf16_t* __restrict__ wq,
        const float* __restrict__ qkv_b,
        const bf16_t* __restrict__ wp,
        const float* __restrict__ proj_b,
        const float* __restrict__ a_p,
        const float* __restrict__ b_p,
        const float* __restrict__ a_r,
        const float* __restrict__ b_r,
        float* __restrict__ out) {
    __shared__ __align__(16) bf16_t sh_xo[64 * 200];        // x, later O (25.6 KB)
    __shared__ __align__(16) bf16_t q_sh[NH][64 * 40];      // per-wave q [token][d]
    __shared__ __align__(16) bf16_t k_sh[NH][64 * 40];      // per-wave k [token][d]
    __shared__ __align__(16) bf16_t vt_sh[NH][32 * 72];     // per-wave v^T [d][token]
    __shared__ __align__(16) bf16_t P_sh[NH][16 * 72];      // per-wave P scratch
    __shared__ float bias_sh[NH][169];

    const int tid  = threadIdx.x;
    const int w    = tid >> 6;        // wave id == head id
    const int lane = tid & 63;
    const int l16  = lane & 15;
    const int quad = lane >> 4;
    const int win  = blockIdx.x;

    bf16_t* q_lds  = q_sh[w];
    bf16_t* k_lds  = k_sh[w];
    bf16_t* vt     = vt_sh[w];
    bf16_t* P      = P_sh[w];
    float*  bias13 = bias_sh[w];

    // ---- Phase 0: stage x (49x192 fp32 -> bf16 LDS, rows 49..63 zeroed) ----
    const float* xg = x + (size_t)win * (NTOK * DIM);
    for (int u = tid; u < 2352; u += 384) {           // 49*192/4
        int e = u * 4;
        int r = e / 192, c = e % 192;
        float4 xv = *(const float4*)(xg + e);
        bf16x4 pk = { (bf16_t)xv.x, (bf16_t)xv.y, (bf16_t)xv.z, (bf16_t)xv.w };
        *(bf16x4*)(&sh_xo[r * 200 + c]) = pk;
    }
    {
        bf16x8 z = {};
        for (int u = tid; u < 360; u += 384) {        // 15*192/8
            int e = u * 8;
            int r = 49 + e / 192, c = e % 192;
            *(bf16x8*)(&sh_xo[r * 200 + c]) = z;
        }
    }
    __syncthreads();

    // ---- Phase 1: x A-frags to registers (shared across q/k/v parts) ----
    bf16x8 af[4][6];
#pragma unroll
    for (int mt = 0; mt < 4; ++mt)
#pragma unroll
        for (int ks = 0; ks < 6; ++ks)
            af[mt][ks] = *(const bf16x8*)(&sh_xo[(mt * 16 + l16) * 200 + ks * 32 + quad * 8]);
    __syncthreads();   // after this, sh_xo may be overwritten with O

    // ---- bias table for this head (per-wave, no barrier needed) ----
    const float Dv = Dp[win];
    for (int u = lane; u < 169; u += 64) {
        int dr = u / 13 - 6, da = u % 13 - 6;
        int ri = (dr < 0) ? dr + 13 : dr;
        int ai = (da < 0) ? da + 13 : da;
        float ang_a = (float)da * (2.0f * PI_F / 56.0f);
        float ang_r = Dv * (float)dr * (2.0f * PI_F / 448.0f);
        bias13[u] = a_p[ai * NH + w] * __cosf(ang_a) + b_p[ai * NH + w] * __sinf(ang_a)
                  + a_r[ri * NH + w] * __cosf(ang_r) + b_r[ri * NH + w] * __sinf(ang_r);
    }

    // ---- Phase 2: QKV gemm for this head (N=32 per part), into private LDS ----
    const float scale = 0.17677669529663687f; // 32^-0.5
    for (int part = 0; part < 3; ++part) {
        const int base_c = part * DIM + w * 32;
        const bf16_t* wg = wq + (size_t)base_c * DIM;
        f32x4 acc[4][2] = {};
#pragma unroll
        for (int ks = 0; ks < 6; ++ks) {
            bf16x8 b0 = *(const bf16x8*)(wg + (size_t)l16 * DIM + ks * 32 + quad * 8);
            bf16x8 b1 = *(const bf16x8*)(wg + (size_t)(16 + l16) * DIM + ks * 32 + quad * 8);
#pragma unroll
            for (int mt = 0; mt < 4; ++mt) {
                acc[mt][0] = __builtin_amdgcn_mfma_f32_16x16x32_bf16(af[mt][ks], b0, acc[mt][0], 0, 0, 0);
                acc[mt][1] = __builtin_amdgcn_mfma_f32_16x16x32_bf16(af[mt][ks], b1, acc[mt][1], 0, 0, 0);
            }
        }
        float bb0 = qkv_b[base_c + l16];
        float bb1 = qkv_b[base_c + 16 + l16];
        if (part == 0) {
#pragma unroll
            for (int mt = 0; mt < 4; ++mt)
#pragma unroll
                for (int r = 0; r < 4; ++r) {
                    int tok = mt * 16 + quad * 4 + r;
                    q_lds[tok * 40 + l16]      = (bf16_t)((acc[mt][0][r] + bb0) * scale);
                    q_lds[tok * 40 + 16 + l16] = (bf16_t)((acc[mt][1][r] + bb1) * scale);
                }
        } else if (part == 1) {
#pragma unroll
            for (int mt = 0; mt < 4; ++mt)
#pragma unroll
                for (int r = 0; r < 4; ++r) {
                    int tok = mt * 16 + quad * 4 + r;
                    k_lds[tok * 40 + l16]      = (bf16_t)(acc[mt][0][r] + bb0);
                    k_lds[tok * 40 + 16 + l16] = (bf16_t)(acc[mt][1][r] + bb1);
                }
        } else {
#pragma unroll
            for (int mt = 0; mt < 4; ++mt)
#pragma unroll
                for (int r = 0; r < 4; ++r) {
                    int tok = mt * 16 + quad * 4 + r;
                    vt[(l16) * 72 + tok]      = (bf16_t)(acc[mt][0][r] + bb0);
                    vt[(16 + l16) * 72 + tok] = (bf16_t)(acc[mt][1][r] + bb1);
                }
        }
    }

    // ---- Phase 3: MFMA attention (R2-verified structure, LDS sources) ----
    bf16x8 kf[4];
#pragma unroll
    for (int nt = 0; nt < 4; ++nt)
        kf[nt] = *(const bf16x8*)(&k_lds[(nt * 16 + l16) * 40 + quad * 8]);
    bf16x8 vf[2][2];
#pragma unroll
    for (int ntd = 0; ntd < 2; ++ntd)
#pragma unroll
        for (int kt = 0; kt < 2; ++kt)
            vf[ntd][kt] = *(const bf16x8*)(&vt[(ntd * 16 + l16) * 72 + kt * 32 + quad * 8]);

    int jh[4], jw[4];
#pragma unroll
    for (int nt = 0; nt < 4; ++nt) {
        int j = nt * 16 + l16;
        jh[nt] = j / 7;
        jw[nt] = j - 7 * jh[nt];
    }

    for (int mt = 0; mt < 4; ++mt) {
        bf16x8 qf = *(const bf16x8*)(&q_lds[(mt * 16 + l16) * 40 + quad * 8]);

        f32x4 s[4] = {};
#pragma unroll
        for (int nt = 0; nt < 4; ++nt)
            s[nt] = __builtin_amdgcn_mfma_f32_16x16x32_bf16(qf, kf[nt], s[nt], 0, 0, 0);

        float ev[4][4];
        float rs[4];
#pragma unroll
        for (int r = 0; r < 4; ++r) {
            int i = mt * 16 + quad * 4 + r;
            int ih = i / 7, iw = i - 7 * ih;
            float val[4];
            float mx = -1e30f;
#pragma unroll
            for (int nt = 0; nt < 4; ++nt) {
                int j = nt * 16 + l16;
                int idx = (ih - jh[nt] + 6) * 13 + (iw - jw[nt] + 6);
                idx = min(max(idx, 0), 168);
                float vv = s[nt][r] + bias13[idx];
                if (j >= 49) vv = -1e30f;
                val[nt] = vv;
                mx = fmaxf(mx, vv);
            }
#pragma unroll
            for (int m = 1; m <= 8; m <<= 1) mx = fmaxf(mx, __shfl_xor(mx, m));
            float sum = 0.f;
#pragma unroll
            for (int nt = 0; nt < 4; ++nt) {
                float e = __expf(val[nt] - mx);
                ev[r][nt] = e;
                sum += e;
            }
#pragma unroll
            for (int m = 1; m <= 8; m <<= 1) sum += __shfl_xor(sum, m);
            rs[r] = 1.0f / sum;
        }

        // P -> per-wave LDS (single-wave RAW: compiler waitcnts, no barrier)
#pragma unroll
        for (int r = 0; r < 4; ++r)
#pragma unroll
            for (int nt = 0; nt < 4; ++nt)
                P[(quad * 4 + r) * 72 + nt * 16 + l16] = (bf16_t)ev[r][nt];

        bf16x8 pa[2];
#pragma unroll
        for (int kt = 0; kt < 2; ++kt)
            pa[kt] = *(const bf16x8*)(&P[l16 * 72 + kt * 32 + quad * 8]);

        f32x4 o[2] = {};
#pragma unroll
        for (int ntd = 0; ntd < 2; ++ntd)
#pragma unroll
            for (int kt = 0; kt < 2; ++kt)
                o[ntd] = __builtin_amdgcn_mfma_f32_16x16x32_bf16(pa[kt], vf[ntd][kt], o[ntd], 0, 0, 0);

        // O (normalized) -> sh_xo rows [token][h*32 + d]
#pragma unroll
        for (int r = 0; r < 4; ++r) {
            int tok = mt * 16 + quad * 4 + r;
            bf16_t* op = &sh_xo[tok * 200 + w * 32];
            op[l16]      = (bf16_t)(o[0][r] * rs[r]);
            op[16 + l16] = (bf16_t)(o[1][r] * rs[r]);
        }
    }

    __syncthreads();   // all heads' O written into sh_xo

    // ---- Phase 4: output projection; wave w covers out channels [w*32, w*32+32) ----
    bf16x8 wf[2][6];
#pragma unroll
    for (int nt = 0; nt < 2; ++nt)
#pragma unroll
        for (int ks = 0; ks < 6; ++ks)
            wf[nt][ks] = *(const bf16x8*)(wp + (size_t)(w * 32 + nt * 16 + l16) * DIM + ks * 32 + quad * 8);

    f32x4 pacc[4][2] = {};
#pragma unroll
    for (int mt = 0; mt < 4; ++mt)
#pragma unroll
        for (int ks = 0; ks < 6; ++ks) {
            bf16x8 oa = *(const bf16x8*)(&sh_xo[(mt * 16 + l16) * 200 + ks * 32 + quad * 8]);
#pragma unroll
            for (int nt = 0; nt < 2; ++nt)
                pacc[mt][nt] = __builtin_amdgcn_mfma_f32_16x16x32_bf16(oa, wf[nt][ks], pacc[mt][nt], 0, 0, 0);
        }

    float pb0 = proj_b[w * 32 + l16];
    float pb1 = proj_b[w * 32 + 16 + l16];
#pragma unroll
    for (int mt = 0; mt < 4; ++mt)
#pragma unroll
        for (int r = 0; r < 4; ++r) {
            int i = mt * 16 + quad * 4 + r;
            if (i < 49) {
                float* op = out + ((size_t)win * NTOK + i) * DIM + w * 32;
                op[l16]      = pacc[mt][0][r] + pb0;
                op[16 + l16] = pacc[mt][1][r] + pb1;
            }
        }
}

extern "C" void kernel_launch(void* const* d_in, const int* in_sizes, int n_in,
                              void* d_out, int out_size, void* d_ws, size_t ws_size,
                              hipStream_t stream) {
    const float* x      = (const float*)d_in[0];
    const float* D      = (const float*)d_in[1];
    const float* qkv_w  = (const float*)d_in[2];
    const float* qkv_b  = (const float*)d_in[3];
    const float* proj_w = (const float*)d_in[4];
    const float* proj_b = (const float*)d_in[5];
    const float* a_p    = (const float*)d_in[6];
    const float* b_p    = (const float*)d_in[7];
    const float* a_r    = (const float*)d_in[8];
    const float* b_r    = (const float*)d_in[9];
    float* out = (float*)d_out;

    const int B_ = in_sizes[0] / (NTOK * DIM);   // 2048 windows

    char* wsp = (char*)d_ws;
    bf16_t* wq = (bf16_t*)wsp; wsp += (size_t)QKV_DIM * DIM * 2;
    bf16_t* wp = (bf16_t*)wsp;

    cvt_weights<<<dim3((QKV_DIM * DIM + DIM * DIM + 255) / 256), dim3(256), 0, stream>>>(
        qkv_w, proj_w, wq, wp);

    fused_win_attn<<<dim3(B_), dim3(384), 0, stream>>>(
        x, D, wq, qkv_b, wp, proj_b, a_p, b_p, a_r, b_r, out);
}